// Round 8
// baseline (268.202 us; speedup 1.0000x reference)
//
#include <hip/hip_runtime.h>
#include <hip/hip_bf16.h>

typedef __attribute__((ext_vector_type(8))) short bf16x8;
typedef __attribute__((ext_vector_type(4))) float f32x4;
typedef __attribute__((ext_vector_type(16))) float f32x16;

#define NTOK 50
#define CDIM 256
#define NH   8
#define SCALE 0.17677669529663687f   // 1/sqrt(32)
#define MFMA32(a,b,c) __builtin_amdgcn_mfma_f32_32x32x16_bf16(a,b,c,0,0,0)
#define Z16 {0.f,0.f,0.f,0.f,0.f,0.f,0.f,0.f,0.f,0.f,0.f,0.f,0.f,0.f,0.f,0.f}

__device__ __forceinline__ unsigned short f2bf(float f) {
  union { __hip_bfloat16 h; unsigned short u; } c;
  c.h = __float2bfloat16(f);  // RNE
  return c.u;
}
__device__ __forceinline__ unsigned pk2(float a, float b) {
  return (unsigned)f2bf(a) | ((unsigned)f2bf(b) << 16);
}

// Exchange primitive (validated r1-r7: absmax 0.0117): packed 32x32 C-tile
// (pk[grp] = regs grp*4+rr over axis value rr+8*grp+4*half) -> MFMA A/B
// fragment for axis chunk c1 (values c1*16 + myh*8 + j). 2 shfl + cndmasks.
__device__ __forceinline__ bf16x8 xchg(uint2 pkA, uint2 pkB, int myh) {
  unsigned ownx = myh ? pkB.x : pkA.x, owny = myh ? pkB.y : pkA.y;
  unsigned crx  = myh ? pkA.x : pkB.x, cry  = myh ? pkA.y : pkB.y;
  crx = (unsigned)__shfl_xor((int)crx, 32);
  cry = (unsigned)__shfl_xor((int)cry, 32);
  union { bf16x8 v; unsigned u[4]; } r;
  r.u[0] = myh ? crx : ownx;
  r.u[1] = myh ? cry : owny;
  r.u[2] = myh ? ownx : crx;
  r.u[3] = myh ? owny : cry;
  return r.v;
}

// Swizzled tile (validated r2-r7: 0 bank conflicts), 512 B row pitch:
// phys_byte(row, col_byte) = row*512 + ((col_byte>>4) ^ (row&31))*16 + (col_byte&15)
__device__ __forceinline__ bf16x8 ld_tile(const char* base, int row, int kc, int myh) {
  int byte = row * 512 + ((((kc << 1) | myh) ^ (row & 31)) << 4);
  return *(const bf16x8*)(base + byte);
}

// prep: W -> bf16 in FRAGMENT order (coalesced dwordx4 streams in main kernel),
// Q rows pre-scaled; biasT in register-order [h][kt][qt][grp][hh][l31][rr] with
// key-mask folded in.
__global__ void prep_kernel(const float* __restrict__ qkv_w, const float* __restrict__ proj_w,
                            const float* __restrict__ bias_table, const int* __restrict__ rel_idx,
                            unsigned short* __restrict__ wq, unsigned short* __restrict__ wp,
                            float* __restrict__ biasT) {
  int i = blockIdx.x * 256 + (int)threadIdx.x;
  if (i < 768 * 256) {
    int row = i >> 8, col = i & 255;
    int mat = row >> 8, h = (row >> 5) & 7, r31 = row & 31;
    int kc = col >> 4, hh = (col >> 3) & 1, j = col & 7;
    int dst = ((((mat * 8 + h) * 16 + kc) * 2 + hh) * 32 + r31) * 8 + j;
    float v = qkv_w[i];
    if (mat == 0) v *= SCALE;
    wq[dst] = f2bf(v);
  }
  if (i < 256 * 256) {
    int row = i >> 8, col = i & 255;
    int wv = row >> 5, r31 = row & 31;
    int kc = col >> 4, hh = (col >> 3) & 1, j = col & 7;
    int dst = (((wv * 16 + kc) * 2 + hh) * 32 + r31) * 8 + j;
    wp[dst] = f2bf(proj_w[i]);
  }
  if (i < 32768) {
    int h = i >> 12, kt = (i >> 11) & 1, qt = (i >> 10) & 1;
    int grp = (i >> 8) & 3, hh = (i >> 7) & 1, l31 = (i >> 2) & 31, rr = i & 3;
    int key = kt * 32 + grp * 8 + hh * 4 + rr;
    int query = qt * 32 + l31;
    float v;
    if (key >= NTOK) v = -1e30f;                               // padded keys: softmax mask
    else if (query == 0 || key == 0 || query >= NTOK) v = 0.f; // region token row/col
    else v = bias_table[rel_idx[(query - 1) * 49 + (key - 1)] * NH + h];
    biasT[i] = v;
  }
}

// HALF-WINDOW blocks: grid 4096 = 2048 windows x 2 query-halves. 256 thr /
// 4 waves; wave w handles heads w, w+4 over 2 passes. Per block: Q for its
// 32 queries only (Qf 16 regs, ONE softmax), K/V for all 64 keys (recomputed
// by both halves -- MFMA is 16% utilized, registers are the scarce resource).
// O written to a dedicated LDS O-tile per pass (zero cross-pass reg carry).
// Audited peak ~140 unified regs -> (256,3) 170 cap -> 3 blocks/CU = 12
// waves/CU (r4-r7 plateau was 8 waves/CU). LDS 48 KB x 3 = 144 <= 160.
__global__ __launch_bounds__(256, 3)
void mhsa_kernel(const float* __restrict__ x, const unsigned short* __restrict__ wq,
                 const unsigned short* __restrict__ wp, const float* __restrict__ biasT,
                 const float* __restrict__ qkv_b, const float* __restrict__ proj_b,
                 float* __restrict__ out) {
  __shared__ uint4 shbuf[3072];            // 48 KB = x tile (32 KB) + O tile (16 KB)
  char* base  = (char*)shbuf;              // x: 64 rows x 512 B, swizzled
  char* obase = (char*)shbuf + 32768;      // O: 32 rows x 512 B, swizzled

  const int bw = blockIdx.x >> 1;          // window
  const int hb = blockIdx.x & 1;           // query-half (tokens hb*32 .. +31)
  const int tid = (int)threadIdx.x;
  const int w = tid >> 6;                  // wave id 0..3
  const int lane = tid & 63;
  const int l31 = lane & 31;
  const int myh = lane >> 5;
  const int fragoff = myh * 256 + l31 * 8; // frag elem-offset within a kc slab

  // ---- stage x: all 64 tokens (K/V need them), rows >= 50 zeroed ----
  {
    const float* xb = x + (size_t)bw * NTOK * CDIM;
    #pragma unroll
    for (int i = 0; i < 16; ++i) {
      int flat = i * 256 + tid;
      int row = flat >> 6, c4 = flat & 63;
      uint2 pv = make_uint2(0u, 0u);
      if (row < NTOK) {
        float4 v = *(const float4*)&xb[row * CDIM + c4 * 4];
        pv.x = pk2(v.x, v.y);
        pv.y = pk2(v.z, v.w);
      }
      int byte = row * 512 + ((((c4 >> 1) ^ (row & 31)) << 4) | ((c4 & 1) << 3));
      *(uint2*)(base + byte) = pv;
    }
  }
  __syncthreads();

  #pragma unroll
  for (int pass = 0; pass < 2; ++pass) {
    const int h = w + 4 * pass;
    const unsigned short* wQb = wq + (size_t)h * 8192;
    const unsigned short* wKb = wq + 65536 + (size_t)h * 8192;
    const unsigned short* wVb = wq + 131072 + (size_t)h * 8192;

    // ---- Q GEMM (this half's 32 tokens only): 1 acc tile ----
    bf16x8 Qf[2];
    {
      f32x16 aq = Z16;
      #pragma unroll
      for (int kc = 0; kc < 16; ++kc) {
        bf16x8 wf = *(const bf16x8*)&wQb[kc * 512 + fragoff];
        aq = MFMA32(wf, ld_tile(base, hb * 32 + l31, kc, myh), aq);
      }
      #pragma unroll
      for (int r = 0; r < 16; ++r) {
        int f = (r & 3) + 8 * (r >> 2) + 4 * myh;
        aq[r] += qkv_b[h * 32 + f] * SCALE;
      }
      uint2 p[4];
      #pragma unroll
      for (int gI = 0; gI < 4; ++gI)
        p[gI] = make_uint2(pk2(aq[4*gI], aq[4*gI+1]), pk2(aq[4*gI+2], aq[4*gI+3]));
      Qf[0] = xchg(p[0], p[1], myh);  Qf[1] = xchg(p[2], p[3], myh);
    }

    // ---- K GEMM (all 64 keys): 2 acc tiles ----
    bf16x8 Kf[2][2];
    {
      f32x16 a0 = Z16, a1 = Z16;
      #pragma unroll
      for (int kc = 0; kc < 16; ++kc) {
        bf16x8 wf = *(const bf16x8*)&wKb[kc * 512 + fragoff];
        a0 = MFMA32(wf, ld_tile(base, l31, kc, myh), a0);
        a1 = MFMA32(wf, ld_tile(base, 32 + l31, kc, myh), a1);
      }
      #pragma unroll
      for (int r = 0; r < 16; ++r) {
        int f = (r & 3) + 8 * (r >> 2) + 4 * myh;
        float bk = qkv_b[CDIM + h * 32 + f];
        a0[r] += bk; a1[r] += bk;
      }
      uint2 p[4];
      #pragma unroll
      for (int gI = 0; gI < 4; ++gI)
        p[gI] = make_uint2(pk2(a0[4*gI], a0[4*gI+1]), pk2(a0[4*gI+2], a0[4*gI+3]));
      Kf[0][0] = xchg(p[0], p[1], myh);  Kf[0][1] = xchg(p[2], p[3], myh);
      #pragma unroll
      for (int gI = 0; gI < 4; ++gI)
        p[gI] = make_uint2(pk2(a1[4*gI], a1[4*gI+1]), pk2(a1[4*gI+2], a1[4*gI+3]));
      Kf[1][0] = xchg(p[0], p[1], myh);  Kf[1][1] = xchg(p[2], p[3], myh);
    }

    // ---- V GEMM (all 64 keys): A = x rows, B = Wv^T ----
    bf16x8 Vf[4];
    {
      f32x16 a0 = Z16, a1 = Z16;
      #pragma unroll
      for (int kc = 0; kc < 16; ++kc) {
        bf16x8 wf = *(const bf16x8*)&wVb[kc * 512 + fragoff];
        a0 = MFMA32(ld_tile(base, l31, kc, myh), wf, a0);
        a1 = MFMA32(ld_tile(base, 32 + l31, kc, myh), wf, a1);
      }
      float bv = qkv_b[2 * CDIM + h * 32 + l31];
      #pragma unroll
      for (int r = 0; r < 16; ++r) { a0[r] += bv; a1[r] += bv; }
      uint2 p[4];
      #pragma unroll
      for (int gI = 0; gI < 4; ++gI)
        p[gI] = make_uint2(pk2(a0[4*gI], a0[4*gI+1]), pk2(a0[4*gI+2], a0[4*gI+3]));
      Vf[0] = xchg(p[0], p[1], myh);  Vf[1] = xchg(p[2], p[3], myh);
      #pragma unroll
      for (int gI = 0; gI < 4; ++gI)
        p[gI] = make_uint2(pk2(a1[4*gI], a1[4*gI+1]), pk2(a1[4*gI+2], a1[4*gI+3]));
      Vf[2] = xchg(p[0], p[1], myh);  Vf[3] = xchg(p[2], p[3], myh);
    }

    // ---- S^T = K*Q^T (+bias, qt = hb) -> softmax (ONE per pass) -> P -> O ----
    {
      f32x16 s0 = Z16, s1 = Z16;
      s0 = MFMA32(Kf[0][0], Qf[0], s0);  s0 = MFMA32(Kf[0][1], Qf[1], s0);
      s1 = MFMA32(Kf[1][0], Qf[0], s1);  s1 = MFMA32(Kf[1][1], Qf[1], s1);
      #pragma unroll
      for (int kt = 0; kt < 2; ++kt) {
        const float* bT = biasT + (size_t)(((h * 2 + kt) * 2 + hb) * 1024);
        #pragma unroll
        for (int gI = 0; gI < 4; ++gI) {
          f32x4 bv = *(const f32x4*)&bT[(gI * 2 + myh) * 128 + l31 * 4];
          if (kt == 0) { s0[4*gI] += bv[0]; s0[4*gI+1] += bv[1]; s0[4*gI+2] += bv[2]; s0[4*gI+3] += bv[3]; }
          else         { s1[4*gI] += bv[0]; s1[4*gI+1] += bv[1]; s1[4*gI+2] += bv[2]; s1[4*gI+3] += bv[3]; }
        }
      }
      // softmax over 64 keys: 32 lane-local + one cross-half shfl
      float mx = -3e38f;
      #pragma unroll
      for (int r = 0; r < 16; ++r) { mx = fmaxf(mx, s0[r]); mx = fmaxf(mx, s1[r]); }
      mx = fmaxf(mx, __shfl_xor(mx, 32));
      float sum = 0.f;
      #pragma unroll
      for (int r = 0; r < 16; ++r) {
        float e0 = __expf(s0[r] - mx); s0[r] = e0; sum += e0;
        float e1 = __expf(s1[r] - mx); s1[r] = e1; sum += e1;
      }
      sum += __shfl_xor(sum, 32);
      float inv = 1.f / sum;
      f32x16 o = Z16;
      {
        uint2 pp[4];
        #pragma unroll
        for (int gI = 0; gI < 4; ++gI)
          pp[gI] = make_uint2(pk2(s0[4*gI]*inv, s0[4*gI+1]*inv), pk2(s0[4*gI+2]*inv, s0[4*gI+3]*inv));
        o = MFMA32(xchg(pp[0], pp[1], myh), Vf[0], o);
        o = MFMA32(xchg(pp[2], pp[3], myh), Vf[1], o);
        #pragma unroll
        for (int gI = 0; gI < 4; ++gI)
          pp[gI] = make_uint2(pk2(s1[4*gI]*inv, s1[4*gI+1]*inv), pk2(s1[4*gI+2]*inv, s1[4*gI+3]*inv));
        o = MFMA32(xchg(pp[0], pp[1], myh), Vf[2], o);
        o = MFMA32(xchg(pp[2], pp[3], myh), Vf[3], o);
      }
      // ---- O tile -> LDS immediately (cols h*32+l31, local rows 0..31):
      // no cross-pass register carry. Waves write disjoint columns.
      const int slotbase = (h << 2) | (l31 >> 3);
      #pragma unroll
      for (int r = 0; r < 16; ++r) {
        int t = (r & 3) + 8 * (r >> 2) + 4 * myh;       // local token 0..31
        int byte = t * 512 + (((slotbase ^ t) << 4) | ((l31 & 7) << 1));
        *(unsigned short*)(obase + byte) = f2bf(o[r]);
      }
    }
  }

  __syncthreads();   // O tile complete (all heads)

  // ---- proj: out[hb*32+t, :] = O_tile * Wp^T + pb; wave owns e-cols [64w, 64w+64) ----
  {
    const unsigned short* wPb0 = wp + (size_t)(2 * w) * 8192;
    const unsigned short* wPb1 = wp + (size_t)(2 * w + 1) * 8192;
    f32x16 po0 = Z16, po1 = Z16;
    #pragma unroll
    for (int kc = 0; kc < 16; ++kc) {
      bf16x8 of = ld_tile(obase, l31, kc, myh);
      bf16x8 w0 = *(const bf16x8*)&wPb0[kc * 512 + fragoff];
      bf16x8 w1 = *(const bf16x8*)&wPb1[kc * 512 + fragoff];
      po0 = MFMA32(of, w0, po0);
      po1 = MFMA32(of, w1, po1);
    }
    const float pb0 = proj_b[(2 * w) * 32 + l31];
    const float pb1 = proj_b[(2 * w + 1) * 32 + l31];
    #pragma unroll
    for (int r = 0; r < 16; ++r) {
      int t = (r & 3) + 8 * (r >> 2) + 4 * myh;         // local token
      int gt = hb * 32 + t;                              // global token
      if (gt < NTOK) {
        float* orow = out + ((size_t)bw * NTOK + gt) * CDIM;
        orow[(2 * w) * 32 + l31]     = po0[r] + pb0;
        orow[(2 * w + 1) * 32 + l31] = po1[r] + pb1;
      }
    }
  }
}

extern "C" void kernel_launch(void* const* d_in, const int* in_sizes, int n_in,
                              void* d_out, int out_size, void* d_ws, size_t ws_size,
                              hipStream_t stream) {
  const float* x          = (const float*)d_in[0];
  const float* qkv_w      = (const float*)d_in[1];
  const float* qkv_b      = (const float*)d_in[2];
  const float* proj_w     = (const float*)d_in[3];
  const float* proj_b     = (const float*)d_in[4];
  const float* bias_table = (const float*)d_in[5];
  const int*   rel_idx    = (const int*)d_in[6];

  unsigned short* wq = (unsigned short*)d_ws;          // 768*256 bf16, frag-ordered
  unsigned short* wp = wq + 768 * 256;                 // 256*256 bf16, frag-ordered
  float* biasT = (float*)(wp + 256 * 256);             // 32768 f32, frag-ordered

  prep_kernel<<<768, 256, 0, stream>>>(qkv_w, proj_w, bias_table, rel_idx, wq, wp, biasT);
  mhsa_kernel<<<4096, 256, 0, stream>>>(x, wq, wp, biasT, qkv_b, proj_b, (float*)d_out);
}

// Round 9
// 237.861 us; speedup vs baseline: 1.1276x; 1.1276x over previous
//
#include <hip/hip_runtime.h>
#include <hip/hip_bf16.h>

typedef __attribute__((ext_vector_type(8))) short bf16x8;
typedef __attribute__((ext_vector_type(4))) float f32x4;
typedef __attribute__((ext_vector_type(16))) float f32x16;

#define NTOK 50
#define CDIM 256
#define NH   8
#define SCALE 0.17677669529663687f   // 1/sqrt(32)
#define MFMA32(a,b,c) __builtin_amdgcn_mfma_f32_32x32x16_bf16(a,b,c,0,0,0)
#define Z16 {0.f,0.f,0.f,0.f,0.f,0.f,0.f,0.f,0.f,0.f,0.f,0.f,0.f,0.f,0.f,0.f}

__device__ __forceinline__ unsigned short f2bf(float f) {
  union { __hip_bfloat16 h; unsigned short u; } c;
  c.h = __float2bfloat16(f);  // RNE
  return c.u;
}
__device__ __forceinline__ unsigned pk2(float a, float b) {
  return (unsigned)f2bf(a) | ((unsigned)f2bf(b) << 16);
}

// Exchange primitive (validated r1-r8: absmax 0.0117): packed 32x32 C-tile
// (pk[grp] = regs grp*4+rr over axis value rr+8*grp+4*half) -> MFMA A/B
// fragment for axis chunk c1 (values c1*16 + myh*8 + j). 2 shfl + cndmasks.
__device__ __forceinline__ bf16x8 xchg(uint2 pkA, uint2 pkB, int myh) {
  unsigned ownx = myh ? pkB.x : pkA.x, owny = myh ? pkB.y : pkA.y;
  unsigned crx  = myh ? pkA.x : pkB.x, cry  = myh ? pkA.y : pkB.y;
  crx = (unsigned)__shfl_xor((int)crx, 32);
  cry = (unsigned)__shfl_xor((int)cry, 32);
  union { bf16x8 v; unsigned u[4]; } r;
  r.u[0] = myh ? crx : ownx;
  r.u[1] = myh ? cry : owny;
  r.u[2] = myh ? ownx : crx;
  r.u[3] = myh ? owny : cry;
  return r.v;
}

// Swizzled tile (validated r2-r8: 0 bank conflicts), 512 B row pitch:
// phys_byte(row, col_byte) = row*512 + ((col_byte>>4) ^ (row&31))*16 + (col_byte&15)
__device__ __forceinline__ bf16x8 ld_tile(const char* base, int row, int kc, int myh) {
  int byte = row * 512 + ((((kc << 1) | myh) ^ (row & 31)) << 4);
  return *(const bf16x8*)(base + byte);
}

// prep: W -> bf16 in FRAGMENT order (coalesced dwordx4 streams in main kernel),
// Q rows pre-scaled; biasT in register-order [h][kt][qt][grp][hh][l31][rr] with
// key-mask folded in.
__global__ void prep_kernel(const float* __restrict__ qkv_w, const float* __restrict__ proj_w,
                            const float* __restrict__ bias_table, const int* __restrict__ rel_idx,
                            unsigned short* __restrict__ wq, unsigned short* __restrict__ wp,
                            float* __restrict__ biasT) {
  int i = blockIdx.x * 256 + (int)threadIdx.x;
  if (i < 768 * 256) {
    int row = i >> 8, col = i & 255;
    int mat = row >> 8, h = (row >> 5) & 7, r31 = row & 31;
    int kc = col >> 4, hh = (col >> 3) & 1, j = col & 7;
    int dst = ((((mat * 8 + h) * 16 + kc) * 2 + hh) * 32 + r31) * 8 + j;
    float v = qkv_w[i];
    if (mat == 0) v *= SCALE;
    wq[dst] = f2bf(v);
  }
  if (i < 256 * 256) {
    int row = i >> 8, col = i & 255;
    int wv = row >> 5, r31 = row & 31;
    int kc = col >> 4, hh = (col >> 3) & 1, j = col & 7;
    int dst = (((wv * 16 + kc) * 2 + hh) * 32 + r31) * 8 + j;
    wp[dst] = f2bf(proj_w[i]);
  }
  if (i < 32768) {
    int h = i >> 12, kt = (i >> 11) & 1, qt = (i >> 10) & 1;
    int grp = (i >> 8) & 3, hh = (i >> 7) & 1, l31 = (i >> 2) & 31, rr = i & 3;
    int key = kt * 32 + grp * 8 + hh * 4 + rr;
    int query = qt * 32 + l31;
    float v;
    if (key >= NTOK) v = -1e30f;                               // padded keys: softmax mask
    else if (query == 0 || key == 0 || query >= NTOK) v = 0.f; // region token row/col
    else v = bias_table[rel_idx[(query - 1) * 49 + (key - 1)] * NH + h];
    biasT[i] = v;
  }
}

// HALF-WINDOW blocks (r8 structure, validated): grid 4096 = 2048 windows x 2
// query-halves; 256 thr / 4 waves; wave = heads w, w+4 over 2 passes.
// r9 single-variable change vs r8: #pragma unroll 2 on all kc GEMM loops.
// Mechanism: r3/r6/r8 spills (VGPR=84 signature) came from full-unroll letting
// the scheduler hoist unbounded weight/x loads (4 VGPR each) past the 84-arch
// split of the 170 cap. unroll 2 bounds in-flight loads to ~2 iters (~24 VGPR).
// r5 proved deep load-overlap is worth ~0 here, so the cost is only loop SALU.
__global__ __launch_bounds__(256, 3)
void mhsa_kernel(const float* __restrict__ x, const unsigned short* __restrict__ wq,
                 const unsigned short* __restrict__ wp, const float* __restrict__ biasT,
                 const float* __restrict__ qkv_b, const float* __restrict__ proj_b,
                 float* __restrict__ out) {
  __shared__ uint4 shbuf[3072];            // 48 KB = x tile (32 KB) + O tile (16 KB)
  char* base  = (char*)shbuf;              // x: 64 rows x 512 B, swizzled
  char* obase = (char*)shbuf + 32768;      // O: 32 rows x 512 B, swizzled

  const int bw = blockIdx.x >> 1;          // window
  const int hb = blockIdx.x & 1;           // query-half (tokens hb*32 .. +31)
  const int tid = (int)threadIdx.x;
  const int w = tid >> 6;                  // wave id 0..3
  const int lane = tid & 63;
  const int l31 = lane & 31;
  const int myh = lane >> 5;
  const int fragoff = myh * 256 + l31 * 8; // frag elem-offset within a kc slab

  // ---- stage x: all 64 tokens (K/V need them), rows >= 50 zeroed ----
  {
    const float* xb = x + (size_t)bw * NTOK * CDIM;
    #pragma unroll 4
    for (int i = 0; i < 16; ++i) {
      int flat = i * 256 + tid;
      int row = flat >> 6, c4 = flat & 63;
      uint2 pv = make_uint2(0u, 0u);
      if (row < NTOK) {
        float4 v = *(const float4*)&xb[row * CDIM + c4 * 4];
        pv.x = pk2(v.x, v.y);
        pv.y = pk2(v.z, v.w);
      }
      int byte = row * 512 + ((((c4 >> 1) ^ (row & 31)) << 4) | ((c4 & 1) << 3));
      *(uint2*)(base + byte) = pv;
    }
  }
  __syncthreads();

  #pragma unroll
  for (int pass = 0; pass < 2; ++pass) {
    const int h = w + 4 * pass;
    const unsigned short* wQb = wq + (size_t)h * 8192;
    const unsigned short* wKb = wq + 65536 + (size_t)h * 8192;
    const unsigned short* wVb = wq + 131072 + (size_t)h * 8192;

    // ---- Q GEMM (this half's 32 tokens only): 1 acc tile ----
    bf16x8 Qf[2];
    {
      f32x16 aq = Z16;
      #pragma unroll 2
      for (int kc = 0; kc < 16; ++kc) {
        bf16x8 wf = *(const bf16x8*)&wQb[kc * 512 + fragoff];
        aq = MFMA32(wf, ld_tile(base, hb * 32 + l31, kc, myh), aq);
      }
      #pragma unroll
      for (int r = 0; r < 16; ++r) {
        int f = (r & 3) + 8 * (r >> 2) + 4 * myh;
        aq[r] += qkv_b[h * 32 + f] * SCALE;
      }
      uint2 p[4];
      #pragma unroll
      for (int gI = 0; gI < 4; ++gI)
        p[gI] = make_uint2(pk2(aq[4*gI], aq[4*gI+1]), pk2(aq[4*gI+2], aq[4*gI+3]));
      Qf[0] = xchg(p[0], p[1], myh);  Qf[1] = xchg(p[2], p[3], myh);
    }

    // ---- K GEMM (all 64 keys): 2 acc tiles ----
    bf16x8 Kf[2][2];
    {
      f32x16 a0 = Z16, a1 = Z16;
      #pragma unroll 2
      for (int kc = 0; kc < 16; ++kc) {
        bf16x8 wf = *(const bf16x8*)&wKb[kc * 512 + fragoff];
        a0 = MFMA32(wf, ld_tile(base, l31, kc, myh), a0);
        a1 = MFMA32(wf, ld_tile(base, 32 + l31, kc, myh), a1);
      }
      #pragma unroll
      for (int r = 0; r < 16; ++r) {
        int f = (r & 3) + 8 * (r >> 2) + 4 * myh;
        float bk = qkv_b[CDIM + h * 32 + f];
        a0[r] += bk; a1[r] += bk;
      }
      uint2 p[4];
      #pragma unroll
      for (int gI = 0; gI < 4; ++gI)
        p[gI] = make_uint2(pk2(a0[4*gI], a0[4*gI+1]), pk2(a0[4*gI+2], a0[4*gI+3]));
      Kf[0][0] = xchg(p[0], p[1], myh);  Kf[0][1] = xchg(p[2], p[3], myh);
      #pragma unroll
      for (int gI = 0; gI < 4; ++gI)
        p[gI] = make_uint2(pk2(a1[4*gI], a1[4*gI+1]), pk2(a1[4*gI+2], a1[4*gI+3]));
      Kf[1][0] = xchg(p[0], p[1], myh);  Kf[1][1] = xchg(p[2], p[3], myh);
    }

    // ---- V GEMM (all 64 keys): A = x rows, B = Wv^T ----
    bf16x8 Vf[4];
    {
      f32x16 a0 = Z16, a1 = Z16;
      #pragma unroll 2
      for (int kc = 0; kc < 16; ++kc) {
        bf16x8 wf = *(const bf16x8*)&wVb[kc * 512 + fragoff];
        a0 = MFMA32(ld_tile(base, l31, kc, myh), wf, a0);
        a1 = MFMA32(ld_tile(base, 32 + l31, kc, myh), wf, a1);
      }
      float bv = qkv_b[2 * CDIM + h * 32 + l31];
      #pragma unroll
      for (int r = 0; r < 16; ++r) { a0[r] += bv; a1[r] += bv; }
      uint2 p[4];
      #pragma unroll
      for (int gI = 0; gI < 4; ++gI)
        p[gI] = make_uint2(pk2(a0[4*gI], a0[4*gI+1]), pk2(a0[4*gI+2], a0[4*gI+3]));
      Vf[0] = xchg(p[0], p[1], myh);  Vf[1] = xchg(p[2], p[3], myh);
      #pragma unroll
      for (int gI = 0; gI < 4; ++gI)
        p[gI] = make_uint2(pk2(a1[4*gI], a1[4*gI+1]), pk2(a1[4*gI+2], a1[4*gI+3]));
      Vf[2] = xchg(p[0], p[1], myh);  Vf[3] = xchg(p[2], p[3], myh);
    }

    // ---- S^T = K*Q^T (+bias, qt = hb) -> softmax (ONE per pass) -> P -> O ----
    {
      f32x16 s0 = Z16, s1 = Z16;
      s0 = MFMA32(Kf[0][0], Qf[0], s0);  s0 = MFMA32(Kf[0][1], Qf[1], s0);
      s1 = MFMA32(Kf[1][0], Qf[0], s1);  s1 = MFMA32(Kf[1][1], Qf[1], s1);
      #pragma unroll
      for (int kt = 0; kt < 2; ++kt) {
        const float* bT = biasT + (size_t)(((h * 2 + kt) * 2 + hb) * 1024);
        #pragma unroll
        for (int gI = 0; gI < 4; ++gI) {
          f32x4 bv = *(const f32x4*)&bT[(gI * 2 + myh) * 128 + l31 * 4];
          if (kt == 0) { s0[4*gI] += bv[0]; s0[4*gI+1] += bv[1]; s0[4*gI+2] += bv[2]; s0[4*gI+3] += bv[3]; }
          else         { s1[4*gI] += bv[0]; s1[4*gI+1] += bv[1]; s1[4*gI+2] += bv[2]; s1[4*gI+3] += bv[3]; }
        }
      }
      // softmax over 64 keys: 32 lane-local + one cross-half shfl
      float mx = -3e38f;
      #pragma unroll
      for (int r = 0; r < 16; ++r) { mx = fmaxf(mx, s0[r]); mx = fmaxf(mx, s1[r]); }
      mx = fmaxf(mx, __shfl_xor(mx, 32));
      float sum = 0.f;
      #pragma unroll
      for (int r = 0; r < 16; ++r) {
        float e0 = __expf(s0[r] - mx); s0[r] = e0; sum += e0;
        float e1 = __expf(s1[r] - mx); s1[r] = e1; sum += e1;
      }
      sum += __shfl_xor(sum, 32);
      float inv = 1.f / sum;
      f32x16 o = Z16;
      {
        uint2 pp[4];
        #pragma unroll
        for (int gI = 0; gI < 4; ++gI)
          pp[gI] = make_uint2(pk2(s0[4*gI]*inv, s0[4*gI+1]*inv), pk2(s0[4*gI+2]*inv, s0[4*gI+3]*inv));
        o = MFMA32(xchg(pp[0], pp[1], myh), Vf[0], o);
        o = MFMA32(xchg(pp[2], pp[3], myh), Vf[1], o);
        #pragma unroll
        for (int gI = 0; gI < 4; ++gI)
          pp[gI] = make_uint2(pk2(s1[4*gI]*inv, s1[4*gI+1]*inv), pk2(s1[4*gI+2]*inv, s1[4*gI+3]*inv));
        o = MFMA32(xchg(pp[0], pp[1], myh), Vf[2], o);
        o = MFMA32(xchg(pp[2], pp[3], myh), Vf[3], o);
      }
      // ---- O tile -> LDS immediately (cols h*32+l31, local rows 0..31):
      // no cross-pass register carry. Waves write disjoint columns.
      const int slotbase = (h << 2) | (l31 >> 3);
      #pragma unroll
      for (int r = 0; r < 16; ++r) {
        int t = (r & 3) + 8 * (r >> 2) + 4 * myh;       // local token 0..31
        int byte = t * 512 + (((slotbase ^ t) << 4) | ((l31 & 7) << 1));
        *(unsigned short*)(obase + byte) = f2bf(o[r]);
      }
    }
  }

  __syncthreads();   // O tile complete (all heads)

  // ---- proj: out[hb*32+t, :] = O_tile * Wp^T + pb; wave owns e-cols [64w, 64w+64) ----
  {
    const unsigned short* wPb0 = wp + (size_t)(2 * w) * 8192;
    const unsigned short* wPb1 = wp + (size_t)(2 * w + 1) * 8192;
    f32x16 po0 = Z16, po1 = Z16;
    #pragma unroll 2
    for (int kc = 0; kc < 16; ++kc) {
      bf16x8 of = ld_tile(obase, l31, kc, myh);
      bf16x8 w0 = *(const bf16x8*)&wPb0[kc * 512 + fragoff];
      bf16x8 w1 = *(const bf16x8*)&wPb1[kc * 512 + fragoff];
      po0 = MFMA32(of, w0, po0);
      po1 = MFMA32(of, w1, po1);
    }
    const float pb0 = proj_b[(2 * w) * 32 + l31];
    const float pb1 = proj_b[(2 * w + 1) * 32 + l31];
    #pragma unroll
    for (int r = 0; r < 16; ++r) {
      int t = (r & 3) + 8 * (r >> 2) + 4 * myh;         // local token
      int gt = hb * 32 + t;                              // global token
      if (gt < NTOK) {
        float* orow = out + ((size_t)bw * NTOK + gt) * CDIM;
        orow[(2 * w) * 32 + l31]     = po0[r] + pb0;
        orow[(2 * w + 1) * 32 + l31] = po1[r] + pb1;
      }
    }
  }
}

extern "C" void kernel_launch(void* const* d_in, const int* in_sizes, int n_in,
                              void* d_out, int out_size, void* d_ws, size_t ws_size,
                              hipStream_t stream) {
  const float* x          = (const float*)d_in[0];
  const float* qkv_w      = (const float*)d_in[1];
  const float* qkv_b      = (const float*)d_in[2];
  const float* proj_w     = (const float*)d_in[3];
  const float* proj_b     = (const float*)d_in[4];
  const float* bias_table = (const float*)d_in[5];
  const int*   rel_idx    = (const int*)d_in[6];

  unsigned short* wq = (unsigned short*)d_ws;          // 768*256 bf16, frag-ordered
  unsigned short* wp = wq + 768 * 256;                 // 256*256 bf16, frag-ordered
  float* biasT = (float*)(wp + 256 * 256);             // 32768 f32, frag-ordered

  prep_kernel<<<768, 256, 0, stream>>>(qkv_w, proj_w, bias_table, rel_idx, wq, wp, biasT);
  mhsa_kernel<<<4096, 256, 0, stream>>>(x, wq, wp, biasT, qkv_b, proj_b, (float*)d_out);
}

// Round 10
// 154.673 us; speedup vs baseline: 1.7340x; 1.5378x over previous
//
#include <hip/hip_runtime.h>
#include <hip/hip_bf16.h>

typedef __attribute__((ext_vector_type(8))) short bf16x8;
typedef __attribute__((ext_vector_type(4))) float f32x4;
typedef __attribute__((ext_vector_type(16))) float f32x16;

#define NTOK 50
#define CDIM 256
#define NH   8
#define SCALE 0.17677669529663687f   // 1/sqrt(32)
#define MFMA32(a,b,c) __builtin_amdgcn_mfma_f32_32x32x16_bf16(a,b,c,0,0,0)
#define Z16 {0.f,0.f,0.f,0.f,0.f,0.f,0.f,0.f,0.f,0.f,0.f,0.f,0.f,0.f,0.f,0.f}

__device__ __forceinline__ unsigned short f2bf(float f) {
  union { __hip_bfloat16 h; unsigned short u; } c;
  c.h = __float2bfloat16(f);  // RNE
  return c.u;
}
__device__ __forceinline__ unsigned pk2(float a, float b) {
  return (unsigned)f2bf(a) | ((unsigned)f2bf(b) << 16);
}

// Exchange primitive (validated r1-r9): packed 32x32 C-tile -> MFMA A/B frag
// for axis chunk c1 (values c1*16 + myh*8 + j). Used ONLY for P now.
__device__ __forceinline__ bf16x8 xchg(uint2 pkA, uint2 pkB, int myh) {
  unsigned ownx = myh ? pkB.x : pkA.x, owny = myh ? pkB.y : pkA.y;
  unsigned crx  = myh ? pkA.x : pkB.x, cry  = myh ? pkA.y : pkB.y;
  crx = (unsigned)__shfl_xor((int)crx, 32);
  cry = (unsigned)__shfl_xor((int)cry, 32);
  union { bf16x8 v; unsigned u[4]; } r;
  r.u[0] = myh ? crx : ownx;
  r.u[1] = myh ? cry : owny;
  r.u[2] = myh ? ownx : crx;
  r.u[3] = myh ? owny : cry;
  return r.v;
}

// Swizzled [tok][d] tile, 512 B row pitch (validated r2-r9: 0 bank conflicts):
// 16B-slot(row, slotidx) : phys slot = slotidx ^ (row&31)
__device__ __forceinline__ bf16x8 ld_tile(const char* base, int row, int kc, int myh) {
  int byte = row * 512 + ((((kc << 1) | myh) ^ (row & 31)) << 4);
  return *(const bf16x8*)(base + byte);
}
// frag read at head h's d-slice, chunk dc (d = h*32+dc*16+myh*8 .. +7)
__device__ __forceinline__ bf16x8 ld_hd(const char* base, int row, int h, int dc, int myh) {
  int byte = row * 512 + ((((h << 2) + (dc << 1) + myh) ^ (row & 31)) << 4);
  return *(const bf16x8*)(base + byte);
}

// prep: unchanged from r4-r9 (validated). W bf16 frag-ordered, Q pre-scaled,
// biasT frag-ordered with key-mask folded in.
__global__ void prep_kernel(const float* __restrict__ qkv_w, const float* __restrict__ proj_w,
                            const float* __restrict__ bias_table, const int* __restrict__ rel_idx,
                            unsigned short* __restrict__ wq, unsigned short* __restrict__ wp,
                            float* __restrict__ biasT) {
  int i = blockIdx.x * 256 + (int)threadIdx.x;
  if (i < 768 * 256) {
    int row = i >> 8, col = i & 255;
    int mat = row >> 8, h = (row >> 5) & 7, r31 = row & 31;
    int kc = col >> 4, hh = (col >> 3) & 1, j = col & 7;
    int dst = ((((mat * 8 + h) * 16 + kc) * 2 + hh) * 32 + r31) * 8 + j;
    float v = qkv_w[i];
    if (mat == 0) v *= SCALE;
    wq[dst] = f2bf(v);
  }
  if (i < 256 * 256) {
    int row = i >> 8, col = i & 255;
    int wv = row >> 5, r31 = row & 31;
    int kc = col >> 4, hh = (col >> 3) & 1, j = col & 7;
    int dst = (((wv * 16 + kc) * 2 + hh) * 32 + r31) * 8 + j;
    wp[dst] = f2bf(proj_w[i]);
  }
  if (i < 32768) {
    int h = i >> 12, kt = (i >> 11) & 1, qt = (i >> 10) & 1;
    int grp = (i >> 8) & 3, hh = (i >> 7) & 1, l31 = (i >> 2) & 31, rr = i & 3;
    int key = kt * 32 + grp * 8 + hh * 4 + rr;
    int query = qt * 32 + l31;
    float v;
    if (key >= NTOK) v = -1e30f;                               // padded keys: softmax mask
    else if (query == 0 || key == 0 || query >= NTOK) v = 0.f; // region token row/col
    else v = bias_table[rel_idx[(query - 1) * 49 + (key - 1)] * NH + h];
    biasT[i] = v;
  }
}

// 16-WAVE COOPERATIVE BLOCK: 1024 thr / window, grid 2048. Q/K/V live in LDS,
// not registers -> per-phase reg liveness <=~110 -> 128-reg cap (1024,4) ->
// 4 waves/SIMD = 16 waves/CU (2x r4's 8) at HALF r4's per-wave work (72 vs
// 144 MFMA). Wave ws=(h=ws>>1, qh=ws&1): QKV computes tile (rt=qh, ct=h) of
// each matrix; attn phase is barrier-free (each wave reads+overwrites only its
// own [qh-rows x h-cols] region of Q/O). unroll 2 = r9-proven spill control.
__global__ __launch_bounds__(1024, 4)
void mhsa_kernel(const float* __restrict__ x, const unsigned short* __restrict__ wq,
                 const unsigned short* __restrict__ wp, const float* __restrict__ biasT,
                 const float* __restrict__ qkv_b, const float* __restrict__ proj_b,
                 float* __restrict__ out) {
  __shared__ uint4 shbuf[8192];              // 128 KB
  char* xT  = (char*)shbuf;                  // x   : 64 x 512B swizzled
  char* qoT = (char*)shbuf + 32768;          // Q, later O : 64 x 512B swizzled
  char* kT  = (char*)shbuf + 65536;          // K   : 64 x 512B swizzled
  char* vF  = (char*)shbuf + 98304;          // V frag-store: h*4096 + c1*1024 + myh*512 + l31*16 + j*2

  const int bw = blockIdx.x;
  const int tid = (int)threadIdx.x;
  const int ws = tid >> 6;                   // wave 0..15
  const int lane = tid & 63;
  const int l31 = lane & 31;
  const int myh = lane >> 5;
  const int h  = ws >> 1;                    // head
  const int qh = ws & 1;                     // query/row half
  const int fragoff = myh * 256 + l31 * 8;

  // ---- stage x (rows >= 50 zeroed) ----
  {
    const float* xb = x + (size_t)bw * NTOK * CDIM;
    #pragma unroll
    for (int i = 0; i < 4; ++i) {
      int flat = i * 1024 + tid;
      int row = flat >> 6, c4 = flat & 63;
      uint2 pv = make_uint2(0u, 0u);
      if (row < NTOK) {
        float4 v = *(const float4*)&xb[row * CDIM + c4 * 4];
        pv.x = pk2(v.x, v.y);
        pv.y = pk2(v.z, v.w);
      }
      int byte = row * 512 + ((((c4 >> 1) ^ (row & 31)) << 4) | ((c4 & 1) << 3));
      *(uint2*)(xT + byte) = pv;
    }
  }
  __syncthreads();

  // ---- QKV: wave computes tile (rows qh*32.., cols h*32..) of Q, K, V ----
  {
    const unsigned short* wQb = wq + (size_t)h * 8192;
    const unsigned short* wKb = wq + 65536 + (size_t)h * 8192;
    const unsigned short* wVb = wq + 131072 + (size_t)h * 8192;
    const int d = h * 32 + l31;              // this lane's output feature (C col = lane)

    // Q tile -> qoT [tok][d]
    {
      f32x16 a = Z16;
      #pragma unroll 2
      for (int kc = 0; kc < 16; ++kc)
        a = MFMA32(ld_tile(xT, qh * 32 + l31, kc, myh),
                   *(const bf16x8*)&wQb[kc * 512 + fragoff], a);
      const float bq = qkv_b[d] * SCALE;
      #pragma unroll
      for (int r = 0; r < 16; ++r) {
        int row = qh * 32 + (r & 3) + 8 * (r >> 2) + 4 * myh;
        int byte = row * 512 + ((((d >> 3) ^ (row & 31)) << 4) | ((d & 7) << 1));
        *(unsigned short*)(qoT + byte) = f2bf(a[r] + bq);
      }
    }
    // K tile -> kT [tok][d]
    {
      f32x16 a = Z16;
      #pragma unroll 2
      for (int kc = 0; kc < 16; ++kc)
        a = MFMA32(ld_tile(xT, qh * 32 + l31, kc, myh),
                   *(const bf16x8*)&wKb[kc * 512 + fragoff], a);
      const float bk = qkv_b[CDIM + d];
      #pragma unroll
      for (int r = 0; r < 16; ++r) {
        int row = qh * 32 + (r & 3) + 8 * (r >> 2) + 4 * myh;
        int byte = row * 512 + ((((d >> 3) ^ (row & 31)) << 4) | ((d & 7) << 1));
        *(unsigned short*)(kT + byte) = f2bf(a[r] + bk);
      }
    }
    // V tile -> vF in B-FRAG order (k = key token)
    {
      f32x16 a = Z16;
      #pragma unroll 2
      for (int kc = 0; kc < 16; ++kc)
        a = MFMA32(ld_tile(xT, qh * 32 + l31, kc, myh),
                   *(const bf16x8*)&wVb[kc * 512 + fragoff], a);
      const float bv = qkv_b[2 * CDIM + d];
      #pragma unroll
      for (int r = 0; r < 16; ++r) {
        int kg = qh * 32 + (r & 3) + 8 * (r >> 2) + 4 * myh;   // global key
        int byte = h * 4096 + (kg >> 4) * 1024 + ((kg >> 3) & 1) * 512
                 + l31 * 16 + (kg & 7) * 2;
        *(unsigned short*)(vF + byte) = f2bf(a[r] + bv);
      }
    }
  }
  __syncthreads();

  // ---- attention (barrier-free region ownership) ----
  {
    const int qrow = qh * 32 + l31;
    bf16x8 Qf0 = ld_hd(qoT, qrow, h, 0, myh);
    bf16x8 Qf1 = ld_hd(qoT, qrow, h, 1, myh);
    // S^T[key][query] : 2 key-tiles x (K=32 over 2 chunks)
    f32x16 s0 = Z16, s1 = Z16;
    s0 = MFMA32(ld_hd(kT, l31,      h, 0, myh), Qf0, s0);
    s0 = MFMA32(ld_hd(kT, l31,      h, 1, myh), Qf1, s0);
    s1 = MFMA32(ld_hd(kT, 32 + l31, h, 0, myh), Qf0, s1);
    s1 = MFMA32(ld_hd(kT, 32 + l31, h, 1, myh), Qf1, s1);
    // bias add (frag-ordered, qt = qh)
    #pragma unroll
    for (int kt = 0; kt < 2; ++kt) {
      const float* bT = biasT + (size_t)(((h * 2 + kt) * 2 + qh) * 1024);
      #pragma unroll
      for (int gI = 0; gI < 4; ++gI) {
        f32x4 bv = *(const f32x4*)&bT[(gI * 2 + myh) * 128 + l31 * 4];
        if (kt == 0) { s0[4*gI] += bv[0]; s0[4*gI+1] += bv[1]; s0[4*gI+2] += bv[2]; s0[4*gI+3] += bv[3]; }
        else         { s1[4*gI] += bv[0]; s1[4*gI+1] += bv[1]; s1[4*gI+2] += bv[2]; s1[4*gI+3] += bv[3]; }
      }
    }
    // softmax over 64 keys: 32 lane-local + one cross-half shfl
    float mx = -3e38f;
    #pragma unroll
    for (int r = 0; r < 16; ++r) { mx = fmaxf(mx, s0[r]); mx = fmaxf(mx, s1[r]); }
    mx = fmaxf(mx, __shfl_xor(mx, 32));
    float sum = 0.f;
    #pragma unroll
    for (int r = 0; r < 16; ++r) {
      float e0 = __expf(s0[r] - mx); s0[r] = e0; sum += e0;
      float e1 = __expf(s1[r] - mx); s1[r] = e1; sum += e1;
    }
    sum += __shfl_xor(sum, 32);
    const float inv = 1.f / sum;
    // P frags (xchg) x V frags (LDS) -> O
    f32x16 o = Z16;
    {
      uint2 pp[4];
      #pragma unroll
      for (int gI = 0; gI < 4; ++gI)
        pp[gI] = make_uint2(pk2(s0[4*gI]*inv, s0[4*gI+1]*inv), pk2(s0[4*gI+2]*inv, s0[4*gI+3]*inv));
      o = MFMA32(xchg(pp[0], pp[1], myh), *(const bf16x8*)(vF + h*4096 + 0*1024 + myh*512 + l31*16), o);
      o = MFMA32(xchg(pp[2], pp[3], myh), *(const bf16x8*)(vF + h*4096 + 1*1024 + myh*512 + l31*16), o);
      #pragma unroll
      for (int gI = 0; gI < 4; ++gI)
        pp[gI] = make_uint2(pk2(s1[4*gI]*inv, s1[4*gI+1]*inv), pk2(s1[4*gI+2]*inv, s1[4*gI+3]*inv));
      o = MFMA32(xchg(pp[0], pp[1], myh), *(const bf16x8*)(vF + h*4096 + 2*1024 + myh*512 + l31*16), o);
      o = MFMA32(xchg(pp[2], pp[3], myh), *(const bf16x8*)(vF + h*4096 + 3*1024 + myh*512 + l31*16), o);
    }
    // O overwrites this wave's own Q region (rows qh*32.., cols h*32..)
    const int d = h * 32 + l31;
    #pragma unroll
    for (int r = 0; r < 16; ++r) {
      int row = qh * 32 + (r & 3) + 8 * (r >> 2) + 4 * myh;
      int byte = row * 512 + ((((d >> 3) ^ (row & 31)) << 4) | ((d & 7) << 1));
      *(unsigned short*)(qoT + byte) = f2bf(o[r]);
    }
  }
  __syncthreads();

  // ---- proj: wave (rt=qh, ct=h... reuse ws split) computes out tile ----
  {
    const int rt = ws & 1, ct = ws >> 1;
    const unsigned short* wPb = wp + (size_t)ct * 8192;
    f32x16 po = Z16;
    #pragma unroll 2
    for (int kc = 0; kc < 16; ++kc)
      po = MFMA32(ld_tile(qoT, rt * 32 + l31, kc, myh),
                  *(const bf16x8*)&wPb[kc * 512 + fragoff], po);
    const float pb = proj_b[ct * 32 + l31];
    #pragma unroll
    for (int r = 0; r < 16; ++r) {
      int gt = rt * 32 + (r & 3) + 8 * (r >> 2) + 4 * myh;
      if (gt < NTOK)
        out[((size_t)bw * NTOK + gt) * CDIM + ct * 32 + l31] = po[r] + pb;
    }
  }
}

extern "C" void kernel_launch(void* const* d_in, const int* in_sizes, int n_in,
                              void* d_out, int out_size, void* d_ws, size_t ws_size,
                              hipStream_t stream) {
  const float* x          = (const float*)d_in[0];
  const float* qkv_w      = (const float*)d_in[1];
  const float* qkv_b      = (const float*)d_in[2];
  const float* proj_w     = (const float*)d_in[3];
  const float* proj_b     = (const float*)d_in[4];
  const float* bias_table = (const float*)d_in[5];
  const int*   rel_idx    = (const int*)d_in[6];

  unsigned short* wq = (unsigned short*)d_ws;          // 768*256 bf16, frag-ordered
  unsigned short* wp = wq + 768 * 256;                 // 256*256 bf16, frag-ordered
  float* biasT = (float*)(wp + 256 * 256);             // 32768 f32, frag-ordered

  prep_kernel<<<768, 256, 0, stream>>>(qkv_w, proj_w, bias_table, rel_idx, wq, wp, biasT);
  mhsa_kernel<<<2048, 1024, 0, stream>>>(x, wq, wp, biasT, qkv_b, proj_b, (float*)d_out);
}

// Round 11
// 149.014 us; speedup vs baseline: 1.7998x; 1.0380x over previous
//
#include <hip/hip_runtime.h>
#include <hip/hip_bf16.h>

typedef __attribute__((ext_vector_type(8))) short bf16x8;
typedef __attribute__((ext_vector_type(4))) float f32x4;
typedef __attribute__((ext_vector_type(16))) float f32x16;

#define NTOK 50
#define CDIM 256
#define NH   8
#define LOG2E 1.4426950408889634f
#define QSCALE (0.17677669529663687f * 1.4426950408889634f)  // scale * log2e, folded into Q
#define MFMA32(a,b,c) __builtin_amdgcn_mfma_f32_32x32x16_bf16(a,b,c,0,0,0)
#define Z16 {0.f,0.f,0.f,0.f,0.f,0.f,0.f,0.f,0.f,0.f,0.f,0.f,0.f,0.f,0.f,0.f}

__device__ __forceinline__ unsigned short f2bf(float f) {
  union { __hip_bfloat16 h; unsigned short u; } c;
  c.h = __float2bfloat16(f);  // RNE
  return c.u;
}
__device__ __forceinline__ unsigned pk2(float a, float b) {
  return (unsigned)f2bf(a) | ((unsigned)f2bf(b) << 16);
}

// Exchange primitive (validated r1-r10): packed 32x32 C-tile -> MFMA A/B frag.
// Used only for P.
__device__ __forceinline__ bf16x8 xchg(uint2 pkA, uint2 pkB, int myh) {
  unsigned ownx = myh ? pkB.x : pkA.x, owny = myh ? pkB.y : pkA.y;
  unsigned crx  = myh ? pkA.x : pkB.x, cry  = myh ? pkA.y : pkB.y;
  crx = (unsigned)__shfl_xor((int)crx, 32);
  cry = (unsigned)__shfl_xor((int)cry, 32);
  union { bf16x8 v; unsigned u[4]; } r;
  r.u[0] = myh ? crx : ownx;
  r.u[1] = myh ? cry : owny;
  r.u[2] = myh ? ownx : crx;
  r.u[3] = myh ? owny : cry;
  return r.v;
}

// Swizzled [tok][d] tile, 512 B row pitch (validated r2-r10: ~0 bank conflicts)
__device__ __forceinline__ bf16x8 ld_tile(const char* base, int row, int kc, int myh) {
  int byte = row * 512 + ((((kc << 1) | myh) ^ (row & 31)) << 4);
  return *(const bf16x8*)(base + byte);
}
// frag read at head h's d-slice, chunk dc
__device__ __forceinline__ bf16x8 ld_hd(const char* base, int row, int h, int dc, int myh) {
  int byte = row * 512 + ((((h << 2) + (dc << 1) + myh) ^ (row & 31)) << 4);
  return *(const bf16x8*)(base + byte);
}

// prep: W bf16 frag-ordered; Q pre-scaled by scale*log2e (log2-domain softmax);
// biasT frag-ordered, x log2e, key-mask folded in.
__global__ void prep_kernel(const float* __restrict__ qkv_w, const float* __restrict__ proj_w,
                            const float* __restrict__ bias_table, const int* __restrict__ rel_idx,
                            unsigned short* __restrict__ wq, unsigned short* __restrict__ wp,
                            float* __restrict__ biasT) {
  int i = blockIdx.x * 256 + (int)threadIdx.x;
  if (i < 768 * 256) {
    int row = i >> 8, col = i & 255;
    int mat = row >> 8, h = (row >> 5) & 7, r31 = row & 31;
    int kc = col >> 4, hh = (col >> 3) & 1, j = col & 7;
    int dst = ((((mat * 8 + h) * 16 + kc) * 2 + hh) * 32 + r31) * 8 + j;
    float v = qkv_w[i];
    if (mat == 0) v *= QSCALE;
    wq[dst] = f2bf(v);
  }
  if (i < 256 * 256) {
    int row = i >> 8, col = i & 255;
    int wv = row >> 5, r31 = row & 31;
    int kc = col >> 4, hh = (col >> 3) & 1, j = col & 7;
    int dst = (((wv * 16 + kc) * 2 + hh) * 32 + r31) * 8 + j;
    wp[dst] = f2bf(proj_w[i]);
  }
  if (i < 32768) {
    int h = i >> 12, kt = (i >> 11) & 1, qt = (i >> 10) & 1;
    int grp = (i >> 8) & 3, hh = (i >> 7) & 1, l31 = (i >> 2) & 31, rr = i & 3;
    int key = kt * 32 + grp * 8 + hh * 4 + rr;
    int query = qt * 32 + l31;
    float v;
    if (key >= NTOK) v = -1e30f;                               // padded keys: softmax mask
    else if (query == 0 || key == 0 || query >= NTOK) v = 0.f; // region token row/col
    else v = bias_table[rel_idx[(query - 1) * 49 + (key - 1)] * NH + h] * LOG2E;
    biasT[i] = v;
  }
}

// 16-wave cooperative block (r10 structure, 155 us validated). r11 changes:
// (1) FUSED QKV kc-loop: one x-frag read feeds 3 MFMAs -> x LDS reads 48->16
//     b128/wave. 48 AGPR acc + ~45 VGPR < 128 cap; unroll 2 = r9 spill control.
// (2) bias-initialized accumulators (MFMA C-in = bias) -> -64 VALU adds/wave.
// (3) log2-domain softmax (Q,biasT pre-scaled by log2e; native v_exp_f32)
//     -> -32 VALU muls/wave.
__global__ __launch_bounds__(1024, 4)
void mhsa_kernel(const float* __restrict__ x, const unsigned short* __restrict__ wq,
                 const unsigned short* __restrict__ wp, const float* __restrict__ biasT,
                 const float* __restrict__ qkv_b, const float* __restrict__ proj_b,
                 float* __restrict__ out) {
  __shared__ uint4 shbuf[8192];              // 128 KB
  char* xT  = (char*)shbuf;                  // x   : 64 x 512B swizzled
  char* qoT = (char*)shbuf + 32768;          // Q, later O : 64 x 512B swizzled
  char* kT  = (char*)shbuf + 65536;          // K   : 64 x 512B swizzled
  char* vF  = (char*)shbuf + 98304;          // V frag-store

  const int bw = blockIdx.x;
  const int tid = (int)threadIdx.x;
  const int ws = tid >> 6;                   // wave 0..15
  const int lane = tid & 63;
  const int l31 = lane & 31;
  const int myh = lane >> 5;
  const int h  = ws >> 1;                    // head
  const int qh = ws & 1;                     // query/row half
  const int fragoff = myh * 256 + l31 * 8;

  // ---- stage x (rows >= 50 zeroed) ----
  {
    const float* xb = x + (size_t)bw * NTOK * CDIM;
    #pragma unroll
    for (int i = 0; i < 4; ++i) {
      int flat = i * 1024 + tid;
      int row = flat >> 6, c4 = flat & 63;
      uint2 pv = make_uint2(0u, 0u);
      if (row < NTOK) {
        float4 v = *(const float4*)&xb[row * CDIM + c4 * 4];
        pv.x = pk2(v.x, v.y);
        pv.y = pk2(v.z, v.w);
      }
      int byte = row * 512 + ((((c4 >> 1) ^ (row & 31)) << 4) | ((c4 & 1) << 3));
      *(uint2*)(xT + byte) = pv;
    }
  }
  __syncthreads();

  // ---- FUSED QKV: one x-frag read -> 3 MFMAs; acc pre-loaded with bias ----
  {
    const unsigned short* wQb = wq + (size_t)h * 8192;
    const unsigned short* wKb = wq + 65536 + (size_t)h * 8192;
    const unsigned short* wVb = wq + 131072 + (size_t)h * 8192;
    const int d = h * 32 + l31;              // lane's output feature (C col)

    const float bq = qkv_b[d] * QSCALE;
    const float bk = qkv_b[CDIM + d];
    const float bv = qkv_b[2 * CDIM + d];
    f32x16 aQ, aK, aV;
    #pragma unroll
    for (int r = 0; r < 16; ++r) { aQ[r] = bq; aK[r] = bk; aV[r] = bv; }

    #pragma unroll 2
    for (int kc = 0; kc < 16; ++kc) {
      bf16x8 xf = ld_tile(xT, qh * 32 + l31, kc, myh);
      aQ = MFMA32(xf, *(const bf16x8*)&wQb[kc * 512 + fragoff], aQ);
      aK = MFMA32(xf, *(const bf16x8*)&wKb[kc * 512 + fragoff], aK);
      aV = MFMA32(xf, *(const bf16x8*)&wVb[kc * 512 + fragoff], aV);
    }

    // Q tile -> qoT [tok][d]
    #pragma unroll
    for (int r = 0; r < 16; ++r) {
      int row = qh * 32 + (r & 3) + 8 * (r >> 2) + 4 * myh;
      int byte = row * 512 + ((((d >> 3) ^ (row & 31)) << 4) | ((d & 7) << 1));
      *(unsigned short*)(qoT + byte) = f2bf(aQ[r]);
    }
    // K tile -> kT [tok][d]
    #pragma unroll
    for (int r = 0; r < 16; ++r) {
      int row = qh * 32 + (r & 3) + 8 * (r >> 2) + 4 * myh;
      int byte = row * 512 + ((((d >> 3) ^ (row & 31)) << 4) | ((d & 7) << 1));
      *(unsigned short*)(kT + byte) = f2bf(aK[r]);
    }
    // V tile -> vF in B-frag order (k = key token)
    #pragma unroll
    for (int r = 0; r < 16; ++r) {
      int kg = qh * 32 + (r & 3) + 8 * (r >> 2) + 4 * myh;
      int byte = h * 4096 + (kg >> 4) * 1024 + ((kg >> 3) & 1) * 512
               + l31 * 16 + (kg & 7) * 2;
      *(unsigned short*)(vF + byte) = f2bf(aV[r]);
    }
  }
  __syncthreads();

  // ---- attention (barrier-free region ownership) ----
  {
    const int qrow = qh * 32 + l31;
    bf16x8 Qf0 = ld_hd(qoT, qrow, h, 0, myh);
    bf16x8 Qf1 = ld_hd(qoT, qrow, h, 1, myh);
    f32x16 s0 = Z16, s1 = Z16;
    s0 = MFMA32(ld_hd(kT, l31,      h, 0, myh), Qf0, s0);
    s0 = MFMA32(ld_hd(kT, l31,      h, 1, myh), Qf1, s0);
    s1 = MFMA32(ld_hd(kT, 32 + l31, h, 0, myh), Qf0, s1);
    s1 = MFMA32(ld_hd(kT, 32 + l31, h, 1, myh), Qf1, s1);
    // bias add (frag-ordered, log2 domain)
    #pragma unroll
    for (int kt = 0; kt < 2; ++kt) {
      const float* bT = biasT + (size_t)(((h * 2 + kt) * 2 + qh) * 1024);
      #pragma unroll
      for (int gI = 0; gI < 4; ++gI) {
        f32x4 bv = *(const f32x4*)&bT[(gI * 2 + myh) * 128 + l31 * 4];
        if (kt == 0) { s0[4*gI] += bv[0]; s0[4*gI+1] += bv[1]; s0[4*gI+2] += bv[2]; s0[4*gI+3] += bv[3]; }
        else         { s1[4*gI] += bv[0]; s1[4*gI+1] += bv[1]; s1[4*gI+2] += bv[2]; s1[4*gI+3] += bv[3]; }
      }
    }
    // softmax over 64 keys (log2 domain): 32 lane-local + one cross-half shfl
    float mx = -3e38f;
    #pragma unroll
    for (int r = 0; r < 16; ++r) { mx = fmaxf(mx, s0[r]); mx = fmaxf(mx, s1[r]); }
    mx = fmaxf(mx, __shfl_xor(mx, 32));
    float sum = 0.f;
    #pragma unroll
    for (int r = 0; r < 16; ++r) {
      float e0 = __builtin_amdgcn_exp2f(s0[r] - mx); s0[r] = e0; sum += e0;
      float e1 = __builtin_amdgcn_exp2f(s1[r] - mx); s1[r] = e1; sum += e1;
    }
    sum += __shfl_xor(sum, 32);
    const float inv = 1.f / sum;
    // P frags (xchg) x V frags (LDS) -> O
    f32x16 o = Z16;
    {
      uint2 pp[4];
      #pragma unroll
      for (int gI = 0; gI < 4; ++gI)
        pp[gI] = make_uint2(pk2(s0[4*gI]*inv, s0[4*gI+1]*inv), pk2(s0[4*gI+2]*inv, s0[4*gI+3]*inv));
      o = MFMA32(xchg(pp[0], pp[1], myh), *(const bf16x8*)(vF + h*4096 + 0*1024 + myh*512 + l31*16), o);
      o = MFMA32(xchg(pp[2], pp[3], myh), *(const bf16x8*)(vF + h*4096 + 1*1024 + myh*512 + l31*16), o);
      #pragma unroll
      for (int gI = 0; gI < 4; ++gI)
        pp[gI] = make_uint2(pk2(s1[4*gI]*inv, s1[4*gI+1]*inv), pk2(s1[4*gI+2]*inv, s1[4*gI+3]*inv));
      o = MFMA32(xchg(pp[0], pp[1], myh), *(const bf16x8*)(vF + h*4096 + 2*1024 + myh*512 + l31*16), o);
      o = MFMA32(xchg(pp[2], pp[3], myh), *(const bf16x8*)(vF + h*4096 + 3*1024 + myh*512 + l31*16), o);
    }
    // O overwrites this wave's own Q region
    const int d = h * 32 + l31;
    #pragma unroll
    for (int r = 0; r < 16; ++r) {
      int row = qh * 32 + (r & 3) + 8 * (r >> 2) + 4 * myh;
      int byte = row * 512 + ((((d >> 3) ^ (row & 31)) << 4) | ((d & 7) << 1));
      *(unsigned short*)(qoT + byte) = f2bf(o[r]);
    }
  }
  __syncthreads();

  // ---- proj: wave (rt, ct) computes out tile ----
  {
    const int rt = ws & 1, ct = ws >> 1;
    const unsigned short* wPb = wp + (size_t)ct * 8192;
    f32x16 po;
    const float pb = proj_b[ct * 32 + l31];
    #pragma unroll
    for (int r = 0; r < 16; ++r) po[r] = pb;   // bias-initialized accumulator
    #pragma unroll 2
    for (int kc = 0; kc < 16; ++kc)
      po = MFMA32(ld_tile(qoT, rt * 32 + l31, kc, myh),
                  *(const bf16x8*)&wPb[kc * 512 + fragoff], po);
    #pragma unroll
    for (int r = 0; r < 16; ++r) {
      int gt = rt * 32 + (r & 3) + 8 * (r >> 2) + 4 * myh;
      if (gt < NTOK)
        out[((size_t)bw * NTOK + gt) * CDIM + ct * 32 + l31] = po[r];
    }
  }
}

extern "C" void kernel_launch(void* const* d_in, const int* in_sizes, int n_in,
                              void* d_out, int out_size, void* d_ws, size_t ws_size,
                              hipStream_t stream) {
  const float* x          = (const float*)d_in[0];
  const float* qkv_w      = (const float*)d_in[1];
  const float* qkv_b      = (const float*)d_in[2];
  const float* proj_w     = (const float*)d_in[3];
  const float* proj_b     = (const float*)d_in[4];
  const float* bias_table = (const float*)d_in[5];
  const int*   rel_idx    = (const int*)d_in[6];

  unsigned short* wq = (unsigned short*)d_ws;          // 768*256 bf16, frag-ordered
  unsigned short* wp = wq + 768 * 256;                 // 256*256 bf16, frag-ordered
  float* biasT = (float*)(wp + 256 * 256);             // 32768 f32, frag-ordered, log2-domain

  prep_kernel<<<768, 256, 0, stream>>>(qkv_w, proj_w, bias_table, rel_idx, wq, wp, biasT);
  mhsa_kernel<<<2048, 1024, 0, stream>>>(x, wq, wp, biasT, qkv_b, proj_b, (float*)d_out);
}